// Round 6
// baseline (385.365 us; speedup 1.0000x reference)
//
#include <hip/hip_runtime.h>
#include <math.h>

constexpr int cB  = 256;
constexpr int cI  = 512;
constexpr int cR  = 512;
constexpr int cA  = 196;
constexpr int cV  = 10000;
constexpr int cH4 = 2048;   // 4*R

typedef short bf16x8 __attribute__((ext_vector_type(8)));
typedef float f32x4  __attribute__((ext_vector_type(4)));
typedef unsigned short us8 __attribute__((ext_vector_type(8)));

__device__ inline unsigned short f2bf(float f) {
    unsigned int u = __float_as_uint(f);
    u += 0x7fffu + ((u >> 16) & 1u);
    return (unsigned short)(u >> 16);
}
__device__ inline float bf2f(unsigned short s) {
    return __uint_as_float(((unsigned int)s) << 16);
}

// Soft barrier: synchronize LDS only (lgkmcnt), leaving global-load prefetch
// in flight across the barrier. The compiler's __syncthreads emits
// s_waitcnt vmcnt(0) which drains our prefetch (the m97 ~20% stall);
// this is the AITER-style fine-grained alternative.
__device__ inline void soft_barrier() {
    asm volatile("s_waitcnt lgkmcnt(0)\n\ts_barrier" ::: "memory");
}

// ---------------------------------------------------------------------------
// k_cvt4: four fp32->bf16 conversions in one launch (block-range dispatch).
// ---------------------------------------------------------------------------
__global__ __launch_bounds__(256) void k_cvt4(
    const float* __restrict__ s0, unsigned short* __restrict__ d0, int nb0,
    const float* __restrict__ s1, unsigned short* __restrict__ d1, int nb1,
    const float* __restrict__ s2, unsigned short* __restrict__ d2, int nb2,
    const float* __restrict__ s3, unsigned short* __restrict__ d3, int nb3)
{
    int blk = blockIdx.x;
    const float* src; unsigned short* dst; int base;
    if (blk < nb0)                  { src = s0; dst = d0; base = blk; }
    else if (blk < nb0 + nb1)       { src = s1; dst = d1; base = blk - nb0; }
    else if (blk < nb0 + nb1 + nb2) { src = s2; dst = d2; base = blk - nb0 - nb1; }
    else                            { src = s3; dst = d3; base = blk - nb0 - nb1 - nb2; }
    int i = base * 256 + threadIdx.x;
    float4 v = ((const float4*)src)[i];
    ushort4 b;
    b.x = f2bf(v.x); b.y = f2bf(v.y); b.z = f2bf(v.z); b.w = f2bf(v.w);
    ((ushort4*)dst)[i] = b;
}

// ---------------------------------------------------------------------------
// k_ah: out[b,o] = bias[o] + sum_k h[b,k] * W[o,k]   (o < cA)  fp32
// ---------------------------------------------------------------------------
__global__ __launch_bounds__(256) void k_ah(
    const float* __restrict__ h, const float* __restrict__ W,
    const float* __restrict__ bias, float* __restrict__ out)
{
    __shared__ __align__(16) float h_s[cR];
    int b = blockIdx.x;
    int t = threadIdx.x;
    h_s[t]       = h[b * cR + t];
    h_s[t + 256] = h[b * cR + t + 256];
    __syncthreads();
    if (t < cA) {
        const float4* Wv = (const float4*)(W + (size_t)t * cR);
        const float4* hv = (const float4*)h_s;
        float acc = 0.f;
        #pragma unroll 4
        for (int k = 0; k < cR / 4; ++k) {
            float4 w4 = Wv[k], x4 = hv[k];
            acc += w4.x * x4.x + w4.y * x4.y + w4.z * x4.z + w4.w * x4.w;
        }
        out[b * cA + t] = acc + bias[t];
    }
}

// ---------------------------------------------------------------------------
// k_scores_cv: fused GEMM (B*A x 196 x 512) + tanh/dot epilogue, att fp32,
// cvt->bf16 in staging, optional writeback. Pipelined with soft barriers:
// prefetch loads stay in flight across barrier + MFMA phase.
// ---------------------------------------------------------------------------
constexpr int SC_M   = 64;
constexpr int SC_LDA = 72;   // bf16 elems per LDS row (144 B, 2-way alias free)

__global__ __launch_bounds__(256, 3) void k_scores_cv(
    const float* __restrict__ att, unsigned short* __restrict__ att_bf,
    const unsigned short* __restrict__ wa_bf,
    const float* __restrict__ ba, const float* __restrict__ Wd,
    const float* __restrict__ bd, const float* __restrict__ ah,
    float* __restrict__ scores, int wb)
{
    __shared__ __align__(16) unsigned short att_s[SC_M][SC_LDA];
    __shared__ __align__(16) unsigned short wa_s[208][SC_LDA];
    __shared__ float ba_s[208];
    __shared__ float wd_s[208];

    int tid  = threadIdx.x;
    int wave = tid >> 6;
    int lane = tid & 63;
    int lx   = lane & 15;
    int quad = lane >> 4;
    size_t row0 = (size_t)blockIdx.x * SC_M;

    if (tid < 208) {
        ba_s[tid] = (tid < cA) ? ba[tid] : 0.f;
        wd_s[tid] = (tid < cA) ? Wd[tid] : 0.f;
    }

    int a_r = tid >> 4, a_c = (tid & 15) * 4;       // att: rows a_r+16i
    int w_r = tid >> 3, w_c = (tid & 7) * 8;        // wa : rows w_r+32i
    const float* attA = att + (row0 + a_r) * cR + a_c;
    unsigned short* wbA = att_bf + (row0 + a_r) * cR + a_c;

    f32x4 acc[13];
    #pragma unroll
    for (int c = 0; c < 13; ++c) acc[c] = (f32x4){0.f, 0.f, 0.f, 0.f};

    float4 patt[4];
    us8    pwa[7];

    #pragma unroll
    for (int i = 0; i < 4; ++i)
        patt[i] = *(const float4*)(attA + (size_t)i * 16 * cR);
    #pragma unroll
    for (int i = 0; i < 7; ++i) {
        int r = w_r + 32 * i;
        pwa[i] = (r < cA) ? *(const us8*)(wa_bf + (size_t)r * cR + w_c)
                          : (us8){0,0,0,0,0,0,0,0};
    }

    for (int k0 = 0; k0 < cR; k0 += 64) {
        #pragma unroll
        for (int i = 0; i < 4; ++i) {
            float4 v = patt[i];
            ushort4 bv;
            bv.x = f2bf(v.x); bv.y = f2bf(v.y); bv.z = f2bf(v.z); bv.w = f2bf(v.w);
            *(ushort4*)&att_s[a_r + 16 * i][a_c] = bv;
            if (wb)
                *(ushort4*)(wbA + (size_t)i * 16 * cR + k0) = bv;
        }
        #pragma unroll
        for (int i = 0; i < 7; ++i) {
            if (tid + 256 * i < 208 * 8)
                *(us8*)&wa_s[w_r + 32 * i][w_c] = pwa[i];
        }
        if (k0 + 64 < cR) {
            #pragma unroll
            for (int i = 0; i < 4; ++i)
                patt[i] = *(const float4*)(attA + (size_t)i * 16 * cR + k0 + 64);
            #pragma unroll
            for (int i = 0; i < 7; ++i) {
                int r = w_r + 32 * i;
                pwa[i] = (r < cA) ? *(const us8*)(wa_bf + (size_t)r * cR + k0 + 64 + w_c)
                                  : (us8){0,0,0,0,0,0,0,0};
            }
        }
        soft_barrier();
        #pragma unroll
        for (int ks = 0; ks < 2; ++ks) {
            int kb = ks * 32 + quad * 8;
            bf16x8 afr = *(const bf16x8*)&att_s[wave * 16 + lx][kb];
            #pragma unroll
            for (int c = 0; c < 13; ++c) {
                bf16x8 bfr = *(const bf16x8*)&wa_s[c * 16 + lx][kb];
                acc[c] = __builtin_amdgcn_mfma_f32_16x16x32_bf16(afr, bfr, acc[c], 0, 0, 0);
            }
        }
        soft_barrier();
    }

    #pragma unroll
    for (int reg = 0; reg < 4; ++reg) {
        size_t row = row0 + wave * 16 + quad * 4 + reg;
        float ahv = ah[row];
        float part = 0.f;
        #pragma unroll
        for (int c = 0; c < 13; ++c) {
            int col = c * 16 + lx;
            part += tanhf(acc[c][reg] + ba_s[col] + ahv) * wd_s[col];
        }
        part += __shfl_xor(part, 1);
        part += __shfl_xor(part, 2);
        part += __shfl_xor(part, 4);
        part += __shfl_xor(part, 8);
        if (lx == 0) scores[row] = part + bd[0];
    }
}

// ---------------------------------------------------------------------------
// k_scores_bf: same, att already bf16. Pipelined with soft barriers.
// ---------------------------------------------------------------------------
__global__ __launch_bounds__(256, 3) void k_scores_bf(
    const unsigned short* __restrict__ att_bf,
    const unsigned short* __restrict__ wa_bf,
    const float* __restrict__ ba, const float* __restrict__ Wd,
    const float* __restrict__ bd, const float* __restrict__ ah,
    float* __restrict__ scores)
{
    __shared__ __align__(16) unsigned short att_s[SC_M][SC_LDA];
    __shared__ __align__(16) unsigned short wa_s[208][SC_LDA];
    __shared__ float ba_s[208];
    __shared__ float wd_s[208];

    int tid  = threadIdx.x;
    int wave = tid >> 6;
    int lane = tid & 63;
    int lx   = lane & 15;
    int quad = lane >> 4;
    size_t row0 = (size_t)blockIdx.x * SC_M;

    if (tid < 208) {
        ba_s[tid] = (tid < cA) ? ba[tid] : 0.f;
        wd_s[tid] = (tid < cA) ? Wd[tid] : 0.f;
    }

    int w_r = tid >> 3, w_c = (tid & 7) * 8;
    const unsigned short* attA = att_bf + (row0 + w_r) * cR + w_c;

    f32x4 acc[13];
    #pragma unroll
    for (int c = 0; c < 13; ++c) acc[c] = (f32x4){0.f, 0.f, 0.f, 0.f};

    us8 patt[2];
    us8 pwa[7];

    #pragma unroll
    for (int i = 0; i < 2; ++i)
        patt[i] = *(const us8*)(attA + (size_t)i * 32 * cR);
    #pragma unroll
    for (int i = 0; i < 7; ++i) {
        int r = w_r + 32 * i;
        pwa[i] = (r < cA) ? *(const us8*)(wa_bf + (size_t)r * cR + w_c)
                          : (us8){0,0,0,0,0,0,0,0};
    }

    for (int k0 = 0; k0 < cR; k0 += 64) {
        #pragma unroll
        for (int i = 0; i < 2; ++i)
            *(us8*)&att_s[w_r + 32 * i][w_c] = patt[i];
        #pragma unroll
        for (int i = 0; i < 7; ++i) {
            if (tid + 256 * i < 208 * 8)
                *(us8*)&wa_s[w_r + 32 * i][w_c] = pwa[i];
        }
        if (k0 + 64 < cR) {
            #pragma unroll
            for (int i = 0; i < 2; ++i)
                patt[i] = *(const us8*)(attA + (size_t)i * 32 * cR + k0 + 64);
            #pragma unroll
            for (int i = 0; i < 7; ++i) {
                int r = w_r + 32 * i;
                pwa[i] = (r < cA) ? *(const us8*)(wa_bf + (size_t)r * cR + k0 + 64 + w_c)
                                  : (us8){0,0,0,0,0,0,0,0};
            }
        }
        soft_barrier();
        #pragma unroll
        for (int ks = 0; ks < 2; ++ks) {
            int kb = ks * 32 + quad * 8;
            bf16x8 afr = *(const bf16x8*)&att_s[wave * 16 + lx][kb];
            #pragma unroll
            for (int c = 0; c < 13; ++c) {
                bf16x8 bfr = *(const bf16x8*)&wa_s[c * 16 + lx][kb];
                acc[c] = __builtin_amdgcn_mfma_f32_16x16x32_bf16(afr, bfr, acc[c], 0, 0, 0);
            }
        }
        soft_barrier();
    }

    #pragma unroll
    for (int reg = 0; reg < 4; ++reg) {
        size_t row = row0 + wave * 16 + quad * 4 + reg;
        float ahv = ah[row];
        float part = 0.f;
        #pragma unroll
        for (int c = 0; c < 13; ++c) {
            int col = c * 16 + lx;
            part += tanhf(acc[c][reg] + ba_s[col] + ahv) * wd_s[col];
        }
        part += __shfl_xor(part, 1);
        part += __shfl_xor(part, 2);
        part += __shfl_xor(part, 4);
        part += __shfl_xor(part, 8);
        if (lx == 0) scores[row] = part + bd[0];
    }
}

// ---------------------------------------------------------------------------
// softmax helper (256-thread LDS reduce over A scores)
// ---------------------------------------------------------------------------
__device__ inline void softmax_w(const float* scores, int b, int t, float* red,
                                 float* w_s)
{
    float s = (t < cA) ? scores[b * cA + t] : -INFINITY;
    red[t] = s; __syncthreads();
    for (int off = 128; off > 0; off >>= 1) {
        if (t < off) red[t] = fmaxf(red[t], red[t + off]);
        __syncthreads();
    }
    float mx = red[0];
    __syncthreads();
    float e = (t < cA) ? expf(s - mx) : 0.f;
    red[t] = e; __syncthreads();
    for (int off = 128; off > 0; off >>= 1) {
        if (t < off) red[t] += red[t + off];
        __syncthreads();
    }
    float inv = 1.f / red[0];
    if (t < cA) w_s[t] = e * inv;
    __syncthreads();
}

// ---------------------------------------------------------------------------
// k_attres_bf: softmax + weighted sum (+ optional addin -> fused k_add).
// ---------------------------------------------------------------------------
__global__ __launch_bounds__(256) void k_attres_bf(
    const float* __restrict__ scores, const unsigned short* __restrict__ att_bf,
    const float* __restrict__ addin,
    float* __restrict__ out, unsigned short* __restrict__ out_bf)
{
    __shared__ float red[256];
    __shared__ float w_s[cA];
    __shared__ float red2[4][512];
    int b = blockIdx.x, t = threadIdx.x;
    softmax_w(scores, b, t, red, w_s);

    int p = t >> 6, l = t & 63;
    const unsigned short* base = att_bf + (size_t)b * cA * cR + l * 8;
    float acc[8] = {};
    #pragma unroll 7
    for (int a = p; a < cA; a += 4) {
        us8 v = *(const us8*)(base + (size_t)a * cR);
        float w = w_s[a];
        #pragma unroll
        for (int j = 0; j < 8; ++j)
            acc[j] += bf2f(v[j]) * w;
    }
    #pragma unroll
    for (int j = 0; j < 8; ++j)
        red2[p][l * 8 + j] = acc[j];
    __syncthreads();
    #pragma unroll
    for (int rr = 0; rr < 2; ++rr) {
        int r = t + rr * 256;
        float s = red2[0][r] + red2[1][r] + red2[2][r] + red2[3][r];
        if (addin) s += addin[b * cR + r];
        out[b * cR + r] = s;
        out_bf[b * cR + r] = f2bf(s);
    }
}

// fallback (small ws): fp32 att
__global__ __launch_bounds__(256) void k_attres_f32(
    const float* __restrict__ scores, const float* __restrict__ att,
    const float* __restrict__ addin,
    float* __restrict__ out, unsigned short* __restrict__ out_bf)
{
    __shared__ float red[256];
    __shared__ float w_s[cA];
    int b = blockIdx.x, t = threadIdx.x;
    softmax_w(scores, b, t, red, w_s);

    const float* attb = att + (size_t)b * cA * cR + 2 * t;
    float acc0 = 0.f, acc1 = 0.f;
    #pragma unroll 4
    for (int a = 0; a < cA; ++a) {
        float2 u = *(const float2*)(attb + (size_t)a * cR);
        float w = w_s[a];
        acc0 += u.x * w;
        acc1 += u.y * w;
    }
    if (addin) {
        acc0 += addin[b * cR + 2 * t];
        acc1 += addin[b * cR + 2 * t + 1];
    }
    out[b * cR + 2 * t]     = acc0;
    out[b * cR + 2 * t + 1] = acc1;
    out_bf[b * cR + 2 * t]     = f2bf(acc0);
    out_bf[b * cR + 2 * t + 1] = f2bf(acc1);
}

// ---------------------------------------------------------------------------
// k_sums: sums[b,j] = bi+bh+ba + x.Wi + h.Wh + ar.Wa. Tile 32x64,
// grid (8,32)=256 blocks, flattened 24-iter pipelined K-loop, soft barriers.
// ---------------------------------------------------------------------------
__global__ __launch_bounds__(256, 4) void k_sums(
    const unsigned short* __restrict__ x_bf,
    const unsigned short* __restrict__ h_bf,
    const unsigned short* __restrict__ ar_bf,
    const float* __restrict__ Wi, const float* __restrict__ Wh,
    const float* __restrict__ Wa,
    const float* __restrict__ bi, const float* __restrict__ bh,
    const float* __restrict__ ba, float* __restrict__ out)
{
    __shared__ __align__(16) unsigned short a_s[32][SC_LDA];
    __shared__ __align__(16) unsigned short w_s[64][SC_LDA];
    int tid  = threadIdx.x;
    int wave = tid >> 6;
    int lane = tid & 63;
    int lx   = lane & 15;
    int quad = lane >> 4;
    int b0 = blockIdx.x * 32;
    int j0 = blockIdx.y * 64;

    const unsigned short* Aarr[3] = {x_bf, h_bf, ar_bf};
    const float* Warr[3] = {Wi, Wh, Wa};

    int a_r = tid >> 3, a_c = (tid & 7) * 8;
    int w_r = tid >> 4, w_c = (tid & 15) * 4;

    f32x4 acc0 = {0.f, 0.f, 0.f, 0.f}, acc1 = {0.f, 0.f, 0.f, 0.f};

    us8 pa;
    float4 pw[4];
    pa = *(const us8*)(Aarr[0] + (size_t)(b0 + a_r) * cR + a_c);
    #pragma unroll
    for (int i = 0; i < 4; ++i)
        pw[i] = *(const float4*)(Warr[0] + (size_t)(j0 + w_r + 16 * i) * cR + w_c);

    for (int it = 0; it < 24; ++it) {
        *(us8*)&a_s[a_r][a_c] = pa;
        #pragma unroll
        for (int i = 0; i < 4; ++i) {
            float4 v = pw[i];
            ushort4 bv;
            bv.x = f2bf(v.x); bv.y = f2bf(v.y); bv.z = f2bf(v.z); bv.w = f2bf(v.w);
            *(ushort4*)&w_s[w_r + 16 * i][w_c] = bv;
        }
        if (it < 23) {
            int s2 = (it + 1) >> 3, k2 = ((it + 1) & 7) * 64;
            pa = *(const us8*)(Aarr[s2] + (size_t)(b0 + a_r) * cR + k2 + a_c);
            #pragma unroll
            for (int i = 0; i < 4; ++i)
                pw[i] = *(const float4*)(Warr[s2] + (size_t)(j0 + w_r + 16 * i) * cR + k2 + w_c);
        }
        soft_barrier();
        #pragma unroll
        for (int ks = 0; ks < 2; ++ks) {
            int kb = ks * 32 + quad * 8;
            bf16x8 afr0 = *(const bf16x8*)&a_s[lx][kb];
            bf16x8 afr1 = *(const bf16x8*)&a_s[16 + lx][kb];
            bf16x8 bfr  = *(const bf16x8*)&w_s[wave * 16 + lx][kb];
            acc0 = __builtin_amdgcn_mfma_f32_16x16x32_bf16(afr0, bfr, acc0, 0, 0, 0);
            acc1 = __builtin_amdgcn_mfma_f32_16x16x32_bf16(afr1, bfr, acc1, 0, 0, 0);
        }
        soft_barrier();
    }
    int j = j0 + wave * 16 + lx;
    float bsum = bi[j] + bh[j] + ba[j];
    #pragma unroll
    for (int reg = 0; reg < 4; ++reg) {
        int b = b0 + quad * 4 + reg;
        out[(size_t)b * cH4 + j]        = acc0[reg] + bsum;
        out[(size_t)(b + 16) * cH4 + j] = acc1[reg] + bsum;
    }
}

// ---------------------------------------------------------------------------
// k_lin: out[b,j] = bias[j] + in.W[j]. Tile 32x128, grid (8,79), pipelined,
// soft barriers.
// ---------------------------------------------------------------------------
__global__ __launch_bounds__(256, 4) void k_lin(
    const unsigned short* __restrict__ in_bf, const float* __restrict__ W,
    const float* __restrict__ bias, float* __restrict__ out, int N)
{
    __shared__ __align__(16) unsigned short a_s[32][SC_LDA];
    __shared__ __align__(16) unsigned short w_s[128][SC_LDA];
    int tid  = threadIdx.x;
    int wave = tid >> 6;
    int lane = tid & 63;
    int lx   = lane & 15;
    int quad = lane >> 4;
    int b0 = blockIdx.x * 32;
    int j0 = blockIdx.y * 128;
    int mh = wave & 1, nq = wave >> 1;

    int a_r = tid >> 3, a_c = (tid & 7) * 8;
    int w_r = tid >> 4, w_c = (tid & 15) * 4;

    f32x4 acc[4];
    #pragma unroll
    for (int c = 0; c < 4; ++c) acc[c] = (f32x4){0.f, 0.f, 0.f, 0.f};

    us8 pa;
    float4 pw[8];
    pa = *(const us8*)(in_bf + (size_t)(b0 + a_r) * cR + a_c);
    #pragma unroll
    for (int i = 0; i < 8; ++i) {
        int r = j0 + w_r + 16 * i;
        pw[i] = (r < N) ? *(const float4*)(W + (size_t)r * cR + w_c)
                        : make_float4(0.f, 0.f, 0.f, 0.f);
    }

    for (int k0 = 0; k0 < cR; k0 += 64) {
        *(us8*)&a_s[a_r][a_c] = pa;
        #pragma unroll
        for (int i = 0; i < 8; ++i) {
            float4 v = pw[i];
            ushort4 bv;
            bv.x = f2bf(v.x); bv.y = f2bf(v.y); bv.z = f2bf(v.z); bv.w = f2bf(v.w);
            *(ushort4*)&w_s[w_r + 16 * i][w_c] = bv;
        }
        if (k0 + 64 < cR) {
            pa = *(const us8*)(in_bf + (size_t)(b0 + a_r) * cR + k0 + 64 + a_c);
            #pragma unroll
            for (int i = 0; i < 8; ++i) {
                int r = j0 + w_r + 16 * i;
                pw[i] = (r < N) ? *(const float4*)(W + (size_t)r * cR + k0 + 64 + w_c)
                                : make_float4(0.f, 0.f, 0.f, 0.f);
            }
        }
        soft_barrier();
        #pragma unroll
        for (int ks = 0; ks < 2; ++ks) {
            int kb = ks * 32 + quad * 8;
            bf16x8 afr = *(const bf16x8*)&a_s[mh * 16 + lx][kb];
            #pragma unroll
            for (int c = 0; c < 4; ++c) {
                bf16x8 bfr = *(const bf16x8*)&w_s[nq * 64 + c * 16 + lx][kb];
                acc[c] = __builtin_amdgcn_mfma_f32_16x16x32_bf16(afr, bfr, acc[c], 0, 0, 0);
            }
        }
        soft_barrier();
    }
    #pragma unroll
    for (int c = 0; c < 4; ++c) {
        int j = j0 + nq * 64 + c * 16 + lx;
        if (j < N) {
            float bv = bias[j];
            #pragma unroll
            for (int reg = 0; reg < 4; ++reg) {
                int b = b0 + mh * 16 + quad * 4 + reg;
                out[(size_t)b * N + j] = acc[c][reg] + bv;
            }
        }
    }
}

// ---------------------------------------------------------------------------
__global__ __launch_bounds__(256) void k_cell(
    const float* __restrict__ sums, const float* __restrict__ prev_c,
    float* __restrict__ next_c, float* __restrict__ next_h)
{
    int idx = blockIdx.x * 256 + threadIdx.x;
    int b = idx >> 9;
    int j = idx & 511;
    const float* srow = sums + (size_t)b * cH4;
    float ig = 1.f / (1.f + expf(-srow[j]));
    float fg = 1.f / (1.f + expf(-srow[cR + j]));
    float og = 1.f / (1.f + expf(-srow[2 * cR + j]));
    float gt = tanhf(srow[3 * cR + j]);
    float c = fg * prev_c[idx] + ig * gt;
    float hh = og * tanhf(c);
    next_c[idx] = c;
    next_h[idx] = hh;
}

__global__ __launch_bounds__(256) void k_logsoftmax(float* __restrict__ logits)
{
    __shared__ float red[256];
    int b = blockIdx.x, t = threadIdx.x;
    float* row = logits + (size_t)b * cV;
    const float4* row4 = (const float4*)row;
    float mx = -INFINITY;
    for (int v = t; v < cV / 4; v += 256) {
        float4 f = row4[v];
        mx = fmaxf(mx, fmaxf(fmaxf(f.x, f.y), fmaxf(f.z, f.w)));
    }
    red[t] = mx; __syncthreads();
    for (int off = 128; off > 0; off >>= 1) {
        if (t < off) red[t] = fmaxf(red[t], red[t + off]);
        __syncthreads();
    }
    mx = red[0]; __syncthreads();
    float sum = 0.f;
    for (int v = t; v < cV / 4; v += 256) {
        float4 f = row4[v];
        sum += expf(f.x - mx) + expf(f.y - mx) + expf(f.z - mx) + expf(f.w - mx);
    }
    red[t] = sum; __syncthreads();
    for (int off = 128; off > 0; off >>= 1) {
        if (t < off) red[t] += red[t + off];
        __syncthreads();
    }
    float lse = mx + logf(red[0]);
    for (int v = t; v < cV / 4; v += 256) {
        float4 f = row4[v];
        f.x -= lse; f.y -= lse; f.z -= lse; f.w -= lse;
        ((float4*)row)[v] = f;
    }
}

// ---------------------------------------------------------------------------
extern "C" void kernel_launch(void* const* d_in, const int* in_sizes, int n_in,
                              void* d_out, int out_size, void* d_ws, size_t ws_size,
                              hipStream_t stream)
{
    const float* x      = (const float*)d_in[0];
    const float* att    = (const float*)d_in[1];
    const float* prev_c = (const float*)d_in[2];
    const float* prev_h = (const float*)d_in[3];
    const float* W_a2a  = (const float*)d_in[4];
    const float* b_a2a  = (const float*)d_in[5];
    const float* W_h2a  = (const float*)d_in[6];
    const float* b_h2a  = (const float*)d_in[7];
    const float* W_d2d  = (const float*)d_in[8];
    const float* b_d2d  = (const float*)d_in[9];
    const float* W_i2h  = (const float*)d_in[10];
    const float* b_i2h  = (const float*)d_in[11];
    const float* W_a2h  = (const float*)d_in[12];
    const float* b_a2h  = (const float*)d_in[13];
    const float* W_h2h  = (const float*)d_in[14];
    const float* b_h2h  = (const float*)d_in[15];
    const float* W_a2a1 = (const float*)d_in[16];
    const float* b_a2a1 = (const float*)d_in[17];
    const float* W_h2a1 = (const float*)d_in[18];
    const float* b_h2a1 = (const float*)d_in[19];
    const float* W_d2d1 = (const float*)d_in[20];
    const float* b_d2d1 = (const float*)d_in[21];
    const float* W_proj = (const float*)d_in[22];
    const float* b_proj = (const float*)d_in[23];

    float* out_next_c = (float*)d_out;                   // B*R
    float* out_top_h  = out_next_c + (size_t)cB * cR;    // B*R
    float* out_logits = out_top_h  + (size_t)cB * cR;    // B*V

    const size_t ATT_FLOATS = 12845056;   // 25,690,112 bf16
    const size_t NEED_A = (ATT_FLOATS + 1445888) * sizeof(float);
    bool bigws = ws_size >= NEED_A;

    float* ws = (float*)d_ws;
    unsigned short* att_bf = (unsigned short*)ws;         // path A only
    float* p = bigws ? (ws + ATT_FLOATS) : ws;
    unsigned short* wa2a_bf  = (unsigned short*)p;  p += 50176;
    unsigned short* wa2a1_bf = (unsigned short*)p;  p += 50176;
    unsigned short* x_bf     = (unsigned short*)p;  p += 65536;
    unsigned short* h_bf     = (unsigned short*)p;  p += 65536;
    unsigned short* ar1_bf   = (unsigned short*)p;  p += 65536;
    unsigned short* ar2_bf   = (unsigned short*)p;  p += 65536;
    unsigned short* toph_bf  = (unsigned short*)p;  p += 65536;
    float* ws_ah      = p;  p += 50176;
    float* ws_scores  = p;  p += 50176;
    float* ws_attres1 = p;  p += 131072;
    float* ws_attres2 = p;  p += 131072;
    float* ws_sums    = p;  p += 524288;
    float* ws_next_h  = p;  p += 131072;

    // ---- small bf16 conversions (one launch) ----
    k_cvt4<<<452, 256, 0, stream>>>(W_a2a, wa2a_bf, 98,
                                    W_a2a1, wa2a1_bf, 98,
                                    x, x_bf, 128,
                                    prev_h, h_bf, 128);

    // ---- attend 1 (prev_h); fused att fp32->bf16 writeback on path A ----
    k_ah<<<cB, 256, 0, stream>>>(prev_h, W_h2a, b_h2a, ws_ah);
    k_scores_cv<<<(cB * cA) / SC_M, 256, 0, stream>>>(att, att_bf, wa2a_bf,
                                                      b_a2a, W_d2d, b_d2d,
                                                      ws_ah, ws_scores,
                                                      bigws ? 1 : 0);
    if (bigws)
        k_attres_bf<<<cB, 256, 0, stream>>>(ws_scores, att_bf, nullptr,
                                            ws_attres1, ar1_bf);
    else
        k_attres_f32<<<cB, 256, 0, stream>>>(ws_scores, att, nullptr,
                                             ws_attres1, ar1_bf);

    // ---- gates + LSTM cell ----
    k_sums<<<dim3(8, 32), 256, 0, stream>>>(x_bf, h_bf, ar1_bf,
                                            W_i2h, W_h2h, W_a2h,
                                            b_i2h, b_h2h, b_a2h, ws_sums);
    k_cell<<<(cB * cR) / 256, 256, 0, stream>>>(ws_sums, prev_c, out_next_c, ws_next_h);

    // ---- attend 2 (next_h); fused top_h = attres2 + next_h ----
    k_ah<<<cB, 256, 0, stream>>>(ws_next_h, W_h2a1, b_h2a1, ws_ah);
    if (bigws) {
        k_scores_bf<<<(cB * cA) / SC_M, 256, 0, stream>>>(att_bf, wa2a1_bf,
                                                          b_a2a1, W_d2d1, b_d2d1,
                                                          ws_ah, ws_scores);
        k_attres_bf<<<cB, 256, 0, stream>>>(ws_scores, att_bf, ws_next_h,
                                            out_top_h, toph_bf);
    } else {
        k_scores_cv<<<(cB * cA) / SC_M, 256, 0, stream>>>(att, att_bf, wa2a1_bf,
                                                          b_a2a1, W_d2d1, b_d2d1,
                                                          ws_ah, ws_scores, 0);
        k_attres_f32<<<cB, 256, 0, stream>>>(ws_scores, att, ws_next_h,
                                             out_top_h, toph_bf);
    }

    // ---- projection + log_softmax ----
    k_lin<<<dim3(8, 79), 256, 0, stream>>>(toph_bf, W_proj, b_proj, out_logits, cV);
    k_logsoftmax<<<cB, 256, 0, stream>>>(out_logits);
}

// Round 7
// 380.965 us; speedup vs baseline: 1.0115x; 1.0115x over previous
//
#include <hip/hip_runtime.h>
#include <math.h>

constexpr int cB  = 256;
constexpr int cI  = 512;
constexpr int cR  = 512;
constexpr int cA  = 196;
constexpr int cV  = 10000;
constexpr int cH4 = 2048;   // 4*R

typedef short bf16x8 __attribute__((ext_vector_type(8)));
typedef float f32x4  __attribute__((ext_vector_type(4)));
typedef unsigned short us8 __attribute__((ext_vector_type(8)));

__device__ inline unsigned short f2bf(float f) {
    unsigned int u = __float_as_uint(f);
    u += 0x7fffu + ((u >> 16) & 1u);
    return (unsigned short)(u >> 16);
}
__device__ inline float bf2f(unsigned short s) {
    return __uint_as_float(((unsigned int)s) << 16);
}

// ---------------------------------------------------------------------------
// k_cvt4: four fp32->bf16 conversions in one launch.
// ---------------------------------------------------------------------------
__global__ __launch_bounds__(256) void k_cvt4(
    const float* __restrict__ s0, unsigned short* __restrict__ d0, int nb0,
    const float* __restrict__ s1, unsigned short* __restrict__ d1, int nb1,
    const float* __restrict__ s2, unsigned short* __restrict__ d2, int nb2,
    const float* __restrict__ s3, unsigned short* __restrict__ d3, int nb3)
{
    int blk = blockIdx.x;
    const float* src; unsigned short* dst; int base;
    if (blk < nb0)                  { src = s0; dst = d0; base = blk; }
    else if (blk < nb0 + nb1)       { src = s1; dst = d1; base = blk - nb0; }
    else if (blk < nb0 + nb1 + nb2) { src = s2; dst = d2; base = blk - nb0 - nb1; }
    else                            { src = s3; dst = d3; base = blk - nb0 - nb1 - nb2; }
    int i = base * 256 + threadIdx.x;
    float4 v = ((const float4*)src)[i];
    ushort4 b;
    b.x = f2bf(v.x); b.y = f2bf(v.y); b.z = f2bf(v.z); b.w = f2bf(v.w);
    ((ushort4*)dst)[i] = b;
}

// ---------------------------------------------------------------------------
// k_ah: out[b,o] = bias[o] + sum_k h[b,k] * W[o,k]   (o < cA)  fp32
// ---------------------------------------------------------------------------
__global__ __launch_bounds__(256) void k_ah(
    const float* __restrict__ h, const float* __restrict__ W,
    const float* __restrict__ bias, float* __restrict__ out)
{
    __shared__ __align__(16) float h_s[cR];
    int b = blockIdx.x;
    int t = threadIdx.x;
    h_s[t]       = h[b * cR + t];
    h_s[t + 256] = h[b * cR + t + 256];
    __syncthreads();
    if (t < cA) {
        const float4* Wv = (const float4*)(W + (size_t)t * cR);
        const float4* hv = (const float4*)h_s;
        float acc = 0.f;
        #pragma unroll 4
        for (int k = 0; k < cR / 4; ++k) {
            float4 w4 = Wv[k], x4 = hv[k];
            acc += w4.x * x4.x + w4.y * x4.y + w4.z * x4.z + w4.w * x4.w;
        }
        out[b * cA + t] = acc + bias[t];
    }
}

// ---------------------------------------------------------------------------
// k_scores_cv: fused GEMM (B*A x 196 x 512) + tanh/dot epilogue.
// M=128 block, 2x2 wave tiling (wave = 64 rows x 112 cols): B-tile LDS reads
// amplified 2x instead of 4x -> per-work LDS traffic ~2.2x lower (LDS pipe
// was the binding resource: ds_read_b128 ~12cyc/CU vs MFMA 4.85cyc/SIMD).
// att fp32 -> bf16 in staging, optional writeback. Register prefetch,
// plain __syncthreads (inline-asm soft barrier regressed: LLVM drains all
// counters before asm-with-memory-clobber).
// ---------------------------------------------------------------------------
constexpr int SC_LDA = 72;   // bf16 elems per LDS row (144 B, 2-way alias free)

__global__ __launch_bounds__(256, 2) void k_scores_cv(
    const float* __restrict__ att, unsigned short* __restrict__ att_bf,
    const unsigned short* __restrict__ wa_bf,
    const float* __restrict__ ba, const float* __restrict__ Wd,
    const float* __restrict__ bd, const float* __restrict__ ah,
    float* __restrict__ scores, int wb)
{
    __shared__ __align__(16) unsigned short att_s[128][SC_LDA];
    __shared__ __align__(16) unsigned short wa_s[224][SC_LDA];
    __shared__ float ba_s[224];
    __shared__ float wd_s[224];
    __shared__ float part_s[128][2];

    int tid  = threadIdx.x;
    int wave = tid >> 6;
    int lane = tid & 63;
    int lx   = lane & 15;
    int quad = lane >> 4;
    int mg   = wave >> 1;          // row group: rows mg*64 .. +63
    int ng   = wave & 1;           // col group: cols ng*112 .. +111
    size_t row0 = (size_t)blockIdx.x * 128;

    if (tid < 224) {
        ba_s[tid] = (tid < cA) ? ba[tid] : 0.f;
        wd_s[tid] = (tid < cA) ? Wd[tid] : 0.f;
    }

    int a_r = tid >> 4, a_c = (tid & 15) * 4;   // att: rows a_r+16i, i<8
    int w_r = tid >> 3, w_c = (tid & 7) * 8;    // wa : rows w_r+32i, i<7 (224*8=1792=7*256)
    const float* attA = att + (row0 + a_r) * cR + a_c;
    unsigned short* wbA = att_bf + (row0 + a_r) * cR + a_c;

    f32x4 acc[4][7];
    #pragma unroll
    for (int m = 0; m < 4; ++m)
        #pragma unroll
        for (int c = 0; c < 7; ++c) acc[m][c] = (f32x4){0.f, 0.f, 0.f, 0.f};

    float4 patt[8];
    us8    pwa[7];
    #pragma unroll
    for (int i = 0; i < 8; ++i)
        patt[i] = *(const float4*)(attA + (size_t)i * 16 * cR);
    #pragma unroll
    for (int i = 0; i < 7; ++i) {
        int r = w_r + 32 * i;
        pwa[i] = (r < cA) ? *(const us8*)(wa_bf + (size_t)r * cR + w_c)
                          : (us8){0,0,0,0,0,0,0,0};
    }

    for (int k0 = 0; k0 < cR; k0 += 64) {
        #pragma unroll
        for (int i = 0; i < 8; ++i) {
            float4 v = patt[i];
            ushort4 bv;
            bv.x = f2bf(v.x); bv.y = f2bf(v.y); bv.z = f2bf(v.z); bv.w = f2bf(v.w);
            *(ushort4*)&att_s[a_r + 16 * i][a_c] = bv;
            if (wb)
                *(ushort4*)(wbA + (size_t)i * 16 * cR + k0) = bv;
        }
        #pragma unroll
        for (int i = 0; i < 7; ++i)
            *(us8*)&wa_s[w_r + 32 * i][w_c] = pwa[i];
        if (k0 + 64 < cR) {
            #pragma unroll
            for (int i = 0; i < 8; ++i)
                patt[i] = *(const float4*)(attA + (size_t)i * 16 * cR + k0 + 64);
            #pragma unroll
            for (int i = 0; i < 7; ++i) {
                int r = w_r + 32 * i;
                pwa[i] = (r < cA) ? *(const us8*)(wa_bf + (size_t)r * cR + k0 + 64 + w_c)
                                  : (us8){0,0,0,0,0,0,0,0};
            }
        }
        __syncthreads();
        #pragma unroll
        for (int ks = 0; ks < 2; ++ks) {
            int kb = ks * 32 + quad * 8;
            bf16x8 af[4];
            #pragma unroll
            for (int m = 0; m < 4; ++m)
                af[m] = *(const bf16x8*)&att_s[mg * 64 + m * 16 + lx][kb];
            #pragma unroll
            for (int c = 0; c < 7; ++c) {
                bf16x8 bfr = *(const bf16x8*)&wa_s[ng * 112 + c * 16 + lx][kb];
                #pragma unroll
                for (int m = 0; m < 4; ++m)
                    acc[m][c] = __builtin_amdgcn_mfma_f32_16x16x32_bf16(af[m], bfr, acc[m][c], 0, 0, 0);
            }
        }
        __syncthreads();
    }

    // epilogue: D mapping col=lane&15, row=quad*4+reg; cross-wave (ng) reduce
    #pragma unroll
    for (int m = 0; m < 4; ++m) {
        #pragma unroll
        for (int reg = 0; reg < 4; ++reg) {
            int rl = mg * 64 + m * 16 + quad * 4 + reg;
            float ahv = ah[row0 + rl];
            float part = 0.f;
            #pragma unroll
            for (int c = 0; c < 7; ++c) {
                int col = ng * 112 + c * 16 + lx;
                part += tanhf(acc[m][c][reg] + ba_s[col] + ahv) * wd_s[col];
            }
            part += __shfl_xor(part, 1);
            part += __shfl_xor(part, 2);
            part += __shfl_xor(part, 4);
            part += __shfl_xor(part, 8);
            if (lx == 0) part_s[rl][ng] = part;
        }
    }
    __syncthreads();
    if (tid < 128)
        scores[row0 + tid] = part_s[tid][0] + part_s[tid][1] + bd[0];
}

// ---------------------------------------------------------------------------
// k_scores_bf: same structure, att already bf16.
// ---------------------------------------------------------------------------
__global__ __launch_bounds__(256, 2) void k_scores_bf(
    const unsigned short* __restrict__ att_bf,
    const unsigned short* __restrict__ wa_bf,
    const float* __restrict__ ba, const float* __restrict__ Wd,
    const float* __restrict__ bd, const float* __restrict__ ah,
    float* __restrict__ scores)
{
    __shared__ __align__(16) unsigned short att_s[128][SC_LDA];
    __shared__ __align__(16) unsigned short wa_s[224][SC_LDA];
    __shared__ float ba_s[224];
    __shared__ float wd_s[224];
    __shared__ float part_s[128][2];

    int tid  = threadIdx.x;
    int wave = tid >> 6;
    int lane = tid & 63;
    int lx   = lane & 15;
    int quad = lane >> 4;
    int mg   = wave >> 1;
    int ng   = wave & 1;
    size_t row0 = (size_t)blockIdx.x * 128;

    if (tid < 224) {
        ba_s[tid] = (tid < cA) ? ba[tid] : 0.f;
        wd_s[tid] = (tid < cA) ? Wd[tid] : 0.f;
    }

    int a_r = tid >> 3, a_c = (tid & 7) * 8;    // att: rows a_r+32i, i<4
    int w_r = tid >> 3, w_c = (tid & 7) * 8;    // wa : rows w_r+32i, i<7
    const unsigned short* attA = att_bf + (row0 + a_r) * cR + a_c;

    f32x4 acc[4][7];
    #pragma unroll
    for (int m = 0; m < 4; ++m)
        #pragma unroll
        for (int c = 0; c < 7; ++c) acc[m][c] = (f32x4){0.f, 0.f, 0.f, 0.f};

    us8 patt[4];
    us8 pwa[7];
    #pragma unroll
    for (int i = 0; i < 4; ++i)
        patt[i] = *(const us8*)(attA + (size_t)i * 32 * cR);
    #pragma unroll
    for (int i = 0; i < 7; ++i) {
        int r = w_r + 32 * i;
        pwa[i] = (r < cA) ? *(const us8*)(wa_bf + (size_t)r * cR + w_c)
                          : (us8){0,0,0,0,0,0,0,0};
    }

    for (int k0 = 0; k0 < cR; k0 += 64) {
        #pragma unroll
        for (int i = 0; i < 4; ++i)
            *(us8*)&att_s[a_r + 32 * i][a_c] = patt[i];
        #pragma unroll
        for (int i = 0; i < 7; ++i)
            *(us8*)&wa_s[w_r + 32 * i][w_c] = pwa[i];
        if (k0 + 64 < cR) {
            #pragma unroll
            for (int i = 0; i < 4; ++i)
                patt[i] = *(const us8*)(attA + (size_t)i * 32 * cR + k0 + 64);
            #pragma unroll
            for (int i = 0; i < 7; ++i) {
                int r = w_r + 32 * i;
                pwa[i] = (r < cA) ? *(const us8*)(wa_bf + (size_t)r * cR + k0 + 64 + w_c)
                                  : (us8){0,0,0,0,0,0,0,0};
            }
        }
        __syncthreads();
        #pragma unroll
        for (int ks = 0; ks < 2; ++ks) {
            int kb = ks * 32 + quad * 8;
            bf16x8 af[4];
            #pragma unroll
            for (int m = 0; m < 4; ++m)
                af[m] = *(const bf16x8*)&att_s[mg * 64 + m * 16 + lx][kb];
            #pragma unroll
            for (int c = 0; c < 7; ++c) {
                bf16x8 bfr = *(const bf16x8*)&wa_s[ng * 112 + c * 16 + lx][kb];
                #pragma unroll
                for (int m = 0; m < 4; ++m)
                    acc[m][c] = __builtin_amdgcn_mfma_f32_16x16x32_bf16(af[m], bfr, acc[m][c], 0, 0, 0);
            }
        }
        __syncthreads();
    }

    #pragma unroll
    for (int m = 0; m < 4; ++m) {
        #pragma unroll
        for (int reg = 0; reg < 4; ++reg) {
            int rl = mg * 64 + m * 16 + quad * 4 + reg;
            float ahv = ah[row0 + rl];
            float part = 0.f;
            #pragma unroll
            for (int c = 0; c < 7; ++c) {
                int col = ng * 112 + c * 16 + lx;
                part += tanhf(acc[m][c][reg] + ba_s[col] + ahv) * wd_s[col];
            }
            part += __shfl_xor(part, 1);
            part += __shfl_xor(part, 2);
            part += __shfl_xor(part, 4);
            part += __shfl_xor(part, 8);
            if (lx == 0) part_s[rl][ng] = part;
        }
    }
    __syncthreads();
    if (tid < 128)
        scores[row0 + tid] = part_s[tid][0] + part_s[tid][1] + bd[0];
}

// ---------------------------------------------------------------------------
// softmax helper (256-thread LDS reduce over A scores)
// ---------------------------------------------------------------------------
__device__ inline void softmax_w(const float* scores, int b, int t, float* red,
                                 float* w_s)
{
    float s = (t < cA) ? scores[b * cA + t] : -INFINITY;
    red[t] = s; __syncthreads();
    for (int off = 128; off > 0; off >>= 1) {
        if (t < off) red[t] = fmaxf(red[t], red[t + off]);
        __syncthreads();
    }
    float mx = red[0];
    __syncthreads();
    float e = (t < cA) ? expf(s - mx) : 0.f;
    red[t] = e; __syncthreads();
    for (int off = 128; off > 0; off >>= 1) {
        if (t < off) red[t] += red[t + off];
        __syncthreads();
    }
    float inv = 1.f / red[0];
    if (t < cA) w_s[t] = e * inv;
    __syncthreads();
}

// ---------------------------------------------------------------------------
// k_attres_bf: softmax + weighted sum (+ optional addin).
// ---------------------------------------------------------------------------
__global__ __launch_bounds__(256) void k_attres_bf(
    const float* __restrict__ scores, const unsigned short* __restrict__ att_bf,
    const float* __restrict__ addin,
    float* __restrict__ out, unsigned short* __restrict__ out_bf)
{
    __shared__ float red[256];
    __shared__ float w_s[cA];
    __shared__ float red2[4][512];
    int b = blockIdx.x, t = threadIdx.x;
    softmax_w(scores, b, t, red, w_s);

    int p = t >> 6, l = t & 63;
    const unsigned short* base = att_bf + (size_t)b * cA * cR + l * 8;
    float acc[8] = {};
    #pragma unroll 7
    for (int a = p; a < cA; a += 4) {
        us8 v = *(const us8*)(base + (size_t)a * cR);
        float w = w_s[a];
        #pragma unroll
        for (int j = 0; j < 8; ++j)
            acc[j] += bf2f(v[j]) * w;
    }
    #pragma unroll
    for (int j = 0; j < 8; ++j)
        red2[p][l * 8 + j] = acc[j];
    __syncthreads();
    #pragma unroll
    for (int rr = 0; rr < 2; ++rr) {
        int r = t + rr * 256;
        float s = red2[0][r] + red2[1][r] + red2[2][r] + red2[3][r];
        if (addin) s += addin[b * cR + r];
        out[b * cR + r] = s;
        out_bf[b * cR + r] = f2bf(s);
    }
}

// fallback (small ws): fp32 att
__global__ __launch_bounds__(256) void k_attres_f32(
    const float* __restrict__ scores, const float* __restrict__ att,
    const float* __restrict__ addin,
    float* __restrict__ out, unsigned short* __restrict__ out_bf)
{
    __shared__ float red[256];
    __shared__ float w_s[cA];
    int b = blockIdx.x, t = threadIdx.x;
    softmax_w(scores, b, t, red, w_s);

    const float* attb = att + (size_t)b * cA * cR + 2 * t;
    float acc0 = 0.f, acc1 = 0.f;
    #pragma unroll 4
    for (int a = 0; a < cA; ++a) {
        float2 u = *(const float2*)(attb + (size_t)a * cR);
        float w = w_s[a];
        acc0 += u.x * w;
        acc1 += u.y * w;
    }
    if (addin) {
        acc0 += addin[b * cR + 2 * t];
        acc1 += addin[b * cR + 2 * t + 1];
    }
    out[b * cR + 2 * t]     = acc0;
    out[b * cR + 2 * t + 1] = acc1;
    out_bf[b * cR + 2 * t]     = f2bf(acc0);
    out_bf[b * cR + 2 * t + 1] = f2bf(acc1);
}

// ---------------------------------------------------------------------------
// k_sums: sums[b,j] = bi+bh+ba + x.Wi + h.Wh + ar.Wa. Tile 32x64,
// grid (8,32), pipelined, __syncthreads.
// ---------------------------------------------------------------------------
__global__ __launch_bounds__(256, 4) void k_sums(
    const unsigned short* __restrict__ x_bf,
    const unsigned short* __restrict__ h_bf,
    const unsigned short* __restrict__ ar_bf,
    const float* __restrict__ Wi, const float* __restrict__ Wh,
    const float* __restrict__ Wa,
    const float* __restrict__ bi, const float* __restrict__ bh,
    const float* __restrict__ ba, float* __restrict__ out)
{
    __shared__ __align__(16) unsigned short a_s[32][SC_LDA];
    __shared__ __align__(16) unsigned short w_s[64][SC_LDA];
    int tid  = threadIdx.x;
    int wave = tid >> 6;
    int lane = tid & 63;
    int lx   = lane & 15;
    int quad = lane >> 4;
    int b0 = blockIdx.x * 32;
    int j0 = blockIdx.y * 64;

    const unsigned short* Aarr[3] = {x_bf, h_bf, ar_bf};
    const float* Warr[3] = {Wi, Wh, Wa};

    int a_r = tid >> 3, a_c = (tid & 7) * 8;
    int w_r = tid >> 4, w_c = (tid & 15) * 4;

    f32x4 acc0 = {0.f, 0.f, 0.f, 0.f}, acc1 = {0.f, 0.f, 0.f, 0.f};

    us8 pa;
    float4 pw[4];
    pa = *(const us8*)(Aarr[0] + (size_t)(b0 + a_r) * cR + a_c);
    #pragma unroll
    for (int i = 0; i < 4; ++i)
        pw[i] = *(const float4*)(Warr[0] + (size_t)(j0 + w_r + 16 * i) * cR + w_c);

    for (int it = 0; it < 24; ++it) {
        *(us8*)&a_s[a_r][a_c] = pa;
        #pragma unroll
        for (int i = 0; i < 4; ++i) {
            float4 v = pw[i];
            ushort4 bv;
            bv.x = f2bf(v.x); bv.y = f2bf(v.y); bv.z = f2bf(v.z); bv.w = f2bf(v.w);
            *(ushort4*)&w_s[w_r + 16 * i][w_c] = bv;
        }
        if (it < 23) {
            int s2 = (it + 1) >> 3, k2 = ((it + 1) & 7) * 64;
            pa = *(const us8*)(Aarr[s2] + (size_t)(b0 + a_r) * cR + k2 + a_c);
            #pragma unroll
            for (int i = 0; i < 4; ++i)
                pw[i] = *(const float4*)(Warr[s2] + (size_t)(j0 + w_r + 16 * i) * cR + k2 + w_c);
        }
        __syncthreads();
        #pragma unroll
        for (int ks = 0; ks < 2; ++ks) {
            int kb = ks * 32 + quad * 8;
            bf16x8 afr0 = *(const bf16x8*)&a_s[lx][kb];
            bf16x8 afr1 = *(const bf16x8*)&a_s[16 + lx][kb];
            bf16x8 bfr  = *(const bf16x8*)&w_s[wave * 16 + lx][kb];
            acc0 = __builtin_amdgcn_mfma_f32_16x16x32_bf16(afr0, bfr, acc0, 0, 0, 0);
            acc1 = __builtin_amdgcn_mfma_f32_16x16x32_bf16(afr1, bfr, acc1, 0, 0, 0);
        }
        __syncthreads();
    }
    int j = j0 + wave * 16 + lx;
    float bsum = bi[j] + bh[j] + ba[j];
    #pragma unroll
    for (int reg = 0; reg < 4; ++reg) {
        int b = b0 + quad * 4 + reg;
        out[(size_t)b * cH4 + j]        = acc0[reg] + bsum;
        out[(size_t)(b + 16) * cH4 + j] = acc1[reg] + bsum;
    }
}

// ---------------------------------------------------------------------------
// k_lin: out[b,j] = bias[j] + in.W[j]. Tile M=128 x N=64, grid (2,157):
// W_proj read 2x (was 8x = 164 MB L3 traffic). 2x2 wave tiling
// (wave = 64 rows x 32 cols), register prefetch.
// ---------------------------------------------------------------------------
__global__ __launch_bounds__(256, 3) void k_lin(
    const unsigned short* __restrict__ in_bf, const float* __restrict__ W,
    const float* __restrict__ bias, float* __restrict__ out, int N)
{
    __shared__ __align__(16) unsigned short a_s[128][SC_LDA];
    __shared__ __align__(16) unsigned short w_s[64][SC_LDA];
    int tid  = threadIdx.x;
    int wave = tid >> 6;
    int lane = tid & 63;
    int lx   = lane & 15;
    int quad = lane >> 4;
    int mg   = wave >> 1;          // rows mg*64 + m*16, m<4
    int ng   = wave & 1;           // cols ng*32 + c*16, c<2
    int b0 = blockIdx.x * 128;
    int j0 = blockIdx.y * 64;

    int a_r = tid >> 3, a_c = (tid & 7) * 8;    // A: rows a_r+32i, i<4
    int w_r = tid >> 4, w_c = (tid & 15) * 4;   // W: rows w_r+16i, i<4

    f32x4 acc[4][2];
    #pragma unroll
    for (int m = 0; m < 4; ++m)
        #pragma unroll
        for (int c = 0; c < 2; ++c) acc[m][c] = (f32x4){0.f, 0.f, 0.f, 0.f};

    us8 pa[4];
    float4 pw[4];
    #pragma unroll
    for (int i = 0; i < 4; ++i)
        pa[i] = *(const us8*)(in_bf + (size_t)(b0 + a_r + 32 * i) * cR + a_c);
    #pragma unroll
    for (int i = 0; i < 4; ++i) {
        int r = j0 + w_r + 16 * i;
        pw[i] = (r < N) ? *(const float4*)(W + (size_t)r * cR + w_c)
                        : make_float4(0.f, 0.f, 0.f, 0.f);
    }

    for (int k0 = 0; k0 < cR; k0 += 64) {
        #pragma unroll
        for (int i = 0; i < 4; ++i)
            *(us8*)&a_s[a_r + 32 * i][a_c] = pa[i];
        #pragma unroll
        for (int i = 0; i < 4; ++i) {
            float4 v = pw[i];
            ushort4 bv;
            bv.x = f2bf(v.x); bv.y = f2bf(v.y); bv.z = f2bf(v.z); bv.w = f2bf(v.w);
            *(ushort4*)&w_s[w_r + 16 * i][w_c] = bv;
        }
        if (k0 + 64 < cR) {
            #pragma unroll
            for (int i = 0; i < 4; ++i)
                pa[i] = *(const us8*)(in_bf + (size_t)(b0 + a_r + 32 * i) * cR + k0 + 64 + a_c);
            #pragma unroll
            for (int i = 0; i < 4; ++i) {
                int r = j0 + w_r + 16 * i;
                pw[i] = (r < N) ? *(const float4*)(W + (size_t)r * cR + k0 + 64 + w_c)
                                : make_float4(0.f, 0.f, 0.f, 0.f);
            }
        }
        __syncthreads();
        #pragma unroll
        for (int ks = 0; ks < 2; ++ks) {
            int kb = ks * 32 + quad * 8;
            bf16x8 af[4];
            #pragma unroll
            for (int m = 0; m < 4; ++m)
                af[m] = *(const bf16x8*)&a_s[mg * 64 + m * 16 + lx][kb];
            #pragma unroll
            for (int c = 0; c < 2; ++c) {
                bf16x8 bfr = *(const bf16x8*)&w_s[ng * 32 + c * 16 + lx][kb];
                #pragma unroll
                for (int m = 0; m < 4; ++m)
                    acc[m][c] = __builtin_amdgcn_mfma_f32_16x16x32_bf16(af[m], bfr, acc[m][c], 0, 0, 0);
            }
        }
        __syncthreads();
    }
    #pragma unroll
    for (int c = 0; c < 2; ++c) {
        int j = j0 + ng * 32 + c * 16 + lx;
        if (j < N) {
            float bv = bias[j];
            #pragma unroll
            for (int m = 0; m < 4; ++m) {
                #pragma unroll
                for (int reg = 0; reg < 4; ++reg) {
                    int b = b0 + mg * 64 + m * 16 + quad * 4 + reg;
                    out[(size_t)b * N + j] = acc[m][c][reg] + bv;
                }
            }
        }
    }
}

// ---------------------------------------------------------------------------
__global__ __launch_bounds__(256) void k_cell(
    const float* __restrict__ sums, const float* __restrict__ prev_c,
    float* __restrict__ next_c, float* __restrict__ next_h)
{
    int idx = blockIdx.x * 256 + threadIdx.x;
    int b = idx >> 9;
    int j = idx & 511;
    const float* srow = sums + (size_t)b * cH4;
    float ig = 1.f / (1.f + expf(-srow[j]));
    float fg = 1.f / (1.f + expf(-srow[cR + j]));
    float og = 1.f / (1.f + expf(-srow[2 * cR + j]));
    float gt = tanhf(srow[3 * cR + j]);
    float c = fg * prev_c[idx] + ig * gt;
    float hh = og * tanhf(c);
    next_c[idx] = c;
    next_h[idx] = hh;
}

__global__ __launch_bounds__(256) void k_logsoftmax(float* __restrict__ logits)
{
    __shared__ float red[256];
    int b = blockIdx.x, t = threadIdx.x;
    float* row = logits + (size_t)b * cV;
    const float4* row4 = (const float4*)row;
    float mx = -INFINITY;
    for (int v = t; v < cV / 4; v += 256) {
        float4 f = row4[v];
        mx = fmaxf(mx, fmaxf(fmaxf(f.x, f.y), fmaxf(f.z, f.w)));
    }
    red[t] = mx; __syncthreads();
    for (int off = 128; off > 0; off >>= 1) {
        if (t < off) red[t] = fmaxf(red[t], red[t + off]);
        __syncthreads();
    }
    mx = red[0]; __syncthreads();
    float sum = 0.f;
    for (int v = t; v < cV / 4; v += 256) {
        float4 f = row4[v];
        sum += expf(f.x - mx) + expf(f.y - mx) + expf(f.z - mx) + expf(f.w - mx);
    }
    red[t] = sum; __syncthreads();
    for (int off = 128; off > 0; off >>= 1) {
        if (t < off) red[t] += red[t + off];
        __syncthreads();
    }
    float lse = mx + logf(red[0]);
    for (int v = t; v < cV / 4; v += 256) {
        float4 f = row4[v];
        f.x -= lse; f.y -= lse; f.z -= lse; f.w -= lse;
        ((float4*)row)[v] = f;
    }
}

// ---------------------------------------------------------------------------
extern "C" void kernel_launch(void* const* d_in, const int* in_sizes, int n_in,
                              void* d_out, int out_size, void* d_ws, size_t ws_size,
                              hipStream_t stream)
{
    const float* x      = (const float*)d_in[0];
    const float* att    = (const float*)d_in[1];
    const float* prev_c = (const float*)d_in[2];
    const float* prev_h = (const float*)d_in[3];
    const float* W_a2a  = (const float*)d_in[4];
    const float* b_a2a  = (const float*)d_in[5];
    const float* W_h2a  = (const float*)d_in[6];
    const float* b_h2a  = (const float*)d_in[7];
    const float* W_d2d  = (const float*)d_in[8];
    const float* b_d2d  = (const float*)d_in[9];
    const float* W_i2h  = (const float*)d_in[10];
    const float* b_i2h  = (const float*)d_in[11];
    const float* W_a2h  = (const float*)d_in[12];
    const float* b_a2h  = (const float*)d_in[13];
    const float* W_h2h  = (const float*)d_in[14];
    const float* b_h2h  = (const float*)d_in[15];
    const float* W_a2a1 = (const float*)d_in[16];
    const float* b_a2a1 = (const float*)d_in[17];
    const float* W_h2a1 = (const float*)d_in[18];
    const float* b_h2a1 = (const float*)d_in[19];
    const float* W_d2d1 = (const float*)d_in[20];
    const float* b_d2d1 = (const float*)d_in[21];
    const float* W_proj = (const float*)d_in[22];
    const float* b_proj = (const float*)d_in[23];

    float* out_next_c = (float*)d_out;                   // B*R
    float* out_top_h  = out_next_c + (size_t)cB * cR;    // B*R
    float* out_logits = out_top_h  + (size_t)cB * cR;    // B*V

    const size_t ATT_FLOATS = 12845056;   // 25,690,112 bf16
    const size_t NEED_A = (ATT_FLOATS + 1445888) * sizeof(float);
    bool bigws = ws_size >= NEED_A;

    float* ws = (float*)d_ws;
    unsigned short* att_bf = (unsigned short*)ws;         // path A only
    float* p = bigws ? (ws + ATT_FLOATS) : ws;
    unsigned short* wa2a_bf  = (unsigned short*)p;  p += 50176;
    unsigned short* wa2a1_bf = (unsigned short*)p;  p += 50176;
    unsigned short* x_bf     = (unsigned short*)p;  p += 65536;
    unsigned short* h_bf     = (unsigned short*)p;  p += 65536;
    unsigned short* ar1_bf   = (unsigned short*)p;  p += 65536;
    unsigned short* ar2_bf   = (unsigned short*)p;  p += 65536;
    unsigned short* toph_bf  = (unsigned short*)p;  p += 65536;
    float* ws_ah      = p;  p += 50176;
    float* ws_scores  = p;  p += 50176;
    float* ws_attres1 = p;  p += 131072;
    float* ws_attres2 = p;  p += 131072;
    float* ws_sums    = p;  p += 524288;
    float* ws_next_h  = p;  p += 131072;

    // ---- small bf16 conversions (one launch) ----
    k_cvt4<<<452, 256, 0, stream>>>(W_a2a, wa2a_bf, 98,
                                    W_a2a1, wa2a1_bf, 98,
                                    x, x_bf, 128,
                                    prev_h, h_bf, 128);

    // ---- attend 1 (prev_h); fused att fp32->bf16 writeback on path A ----
    k_ah<<<cB, 256, 0, stream>>>(prev_h, W_h2a, b_h2a, ws_ah);
    k_scores_cv<<<(cB * cA) / 128, 256, 0, stream>>>(att, att_bf, wa2a_bf,
                                                     b_a2a, W_d2d, b_d2d,
                                                     ws_ah, ws_scores,
                                                     bigws ? 1 : 0);
    if (bigws)
        k_attres_bf<<<cB, 256, 0, stream>>>(ws_scores, att_bf, nullptr,
                                            ws_attres1, ar1_bf);
    else
        k_attres_f32<<<cB, 256, 0, stream>>>(ws_scores, att, nullptr,
                                             ws_attres1, ar1_bf);

    // ---- gates + LSTM cell ----
    k_sums<<<dim3(8, 32), 256, 0, stream>>>(x_bf, h_bf, ar1_bf,
                                            W_i2h, W_h2h, W_a2h,
                                            b_i2h, b_h2h, b_a2h, ws_sums);
    k_cell<<<(cB * cR) / 256, 256, 0, stream>>>(ws_sums, prev_c, out_next_c, ws_next_h);

    // ---- attend 2 (next_h); fused top_h = attres2 + next_h ----
    k_ah<<<cB, 256, 0, stream>>>(ws_next_h, W_h2a1, b_h2a1, ws_ah);
    if (bigws) {
        k_scores_bf<<<(cB * cA) / 128, 256, 0, stream>>>(att_bf, wa2a1_bf,
                                                         b_a2a1, W_d2d1, b_d2d1,
                                                         ws_ah, ws_scores);
        k_attres_bf<<<cB, 256, 0, stream>>>(ws_scores, att_bf, ws_next_h,
                                            out_top_h, toph_bf);
    } else {
        k_scores_cv<<<(cB * cA) / 128, 256, 0, stream>>>(att, att_bf, wa2a1_bf,
                                                         b_a2a1, W_d2d1, b_d2d1,
                                                         ws_ah, ws_scores, 0);
        k_attres_f32<<<cB, 256, 0, stream>>>(ws_scores, att, ws_next_h,
                                             out_top_h, toph_bf);
    }

    // ---- projection + log_softmax ----
    k_lin<<<dim3(2, 157), 256, 0, stream>>>(toph_bf, W_proj, b_proj, out_logits, cV);
    k_logsoftmax<<<cB, 256, 0, stream>>>(out_logits);
}